// Round 2
// baseline (15219.472 us; speedup 1.0000x reference)
//
#include <hip/hip_runtime.h>
#include <hip/hip_bf16.h>

using bf16 = __hip_bfloat16;

// Problem constants (B=2, 256x256, C=192, heads=6, hd=32, ws=8, shift=4)
constexpr int NTOK = 131072;  // 2*256*256

// ---------------- workspace layout (bytes) — total ~72 MiB ----------------
constexpr size_t OFF_Y  = 0;           // bf16 [2][65536][192]  50,331,648
constexpr size_t OFF_T1 = 50331648;    // f32  [131072][24]     12,582,912
constexpr size_t OFF_T2 = 62914560;    // f32  [131072][24]     12,582,912
constexpr size_t OFF_S0 = 75497472;    // f32  [2][192]         1,536
constexpr size_t OFF_SG = 75499008;    // f32  [2][192]         1,536
constexpr size_t WS_NEEDED = 75500544;

__device__ __forceinline__ int region256(int t) { return t < 248 ? 0 : (t < 252 ? 1 : 2); }

// ---------------- LN1 + LCE conv1x1 192->24 (fused) ----------------
__global__ __launch_bounds__(256) void k_ln_lce1(const float* __restrict__ x, const float* __restrict__ g,
                                                 const float* __restrict__ bb, const float* __restrict__ w,
                                                 const float* __restrict__ bia, float* __restrict__ t1) {
  __shared__ float xl[64][193];
  int wave = threadIdx.x >> 6, lane = threadIdx.x & 63;
  size_t tokbase = (size_t)blockIdx.x * 64;
  for (int t = wave; t < 64; t += 4) {
    const float* xr = x + (tokbase + t) * 192;
    float v0 = xr[lane], v1 = xr[lane + 64], v2 = xr[lane + 128];
    float s = v0 + v1 + v2;
    for (int o = 32; o > 0; o >>= 1) s += __shfl_down(s, o);
    s = __shfl(s, 0);
    float m = s * (1.f / 192.f);
    float d0 = v0 - m, d1 = v1 - m, d2 = v2 - m;
    float q = d0 * d0 + d1 * d1 + d2 * d2;
    for (int o = 32; o > 0; o >>= 1) q += __shfl_down(q, o);
    q = __shfl(q, 0);
    float inv = rsqrtf(q * (1.f / 192.f) + 1e-5f);
    xl[t][lane]       = d0 * inv * g[lane]       + bb[lane];
    xl[t][lane + 64]  = d1 * inv * g[lane + 64]  + bb[lane + 64];
    xl[t][lane + 128] = d2 * inv * g[lane + 128] + bb[lane + 128];
  }
  __syncthreads();
  for (int idx = threadIdx.x; idx < 64 * 24; idx += 256) {
    int n = idx / 24, rr = idx - n * 24;
    const float* wr = w + rr * 192;
    float acc = bia[rr];
    for (int c = 0; c < 192; ++c) acc += xl[n][c] * wr[c];
    t1[(tokbase + n) * 24 + rr] = acc;
  }
}

// ---------------- LCE conv3x3 24->24, zero pad 1 ----------------
__global__ __launch_bounds__(256) void k_lce2(const float* __restrict__ t1, const float* __restrict__ w,
                                              const float* __restrict__ bia, float* __restrict__ t2) {
  int tid = blockIdx.x * 256 + threadIdx.x;
  int ro = tid % 24;
  int pix = tid / 24;  // < 131072
  int b = pix >> 16;
  int p = pix & 65535;
  int h = p >> 8, wcol = p & 255;
  float acc = bia[ro];
  for (int ky = 0; ky < 3; ++ky) {
    int h2 = h + ky - 1;
    if (h2 < 0 || h2 > 255) continue;
    for (int kx = 0; kx < 3; ++kx) {
      int w2c = wcol + kx - 1;
      if (w2c < 0 || w2c > 255) continue;
      const float* ir = t1 + ((size_t)(b << 16) + (h2 << 8) + w2c) * 24;
      const float* wr = w + ro * 216 + ky * 3 + kx;  // ((ro*24+ri)*3+ky)*3+kx
      for (int ri = 0; ri < 24; ++ri) acc += ir[ri] * wr[ri * 9];
    }
  }
  t2[(size_t)pix * 24 + ro] = acc;
}

// ---------------- LCE conv1x1 24->192 + LeakyReLU(0.2) -> y (bf16) ----------------
__global__ __launch_bounds__(256) void k_lce3(const float* __restrict__ t2, const float* __restrict__ w,
                                              const float* __restrict__ bia, bf16* __restrict__ y) {
  size_t tid = (size_t)blockIdx.x * 256 + threadIdx.x;  // < 25165824
  int c = (int)(tid % 192);
  size_t pix = tid / 192;
  const float* ir = t2 + pix * 24;
  const float* wr = w + c * 24;
  float acc = bia[c];
  for (int ri = 0; ri < 24; ++ri) acc += ir[ri] * wr[ri];
  if (acc < 0.f) acc *= 0.2f;
  y[tid] = __float2bfloat16(acc);
}

// ---------------- global avg pool partial sums ----------------
__global__ __launch_bounds__(192) void k_pool(const bf16* __restrict__ y, float* __restrict__ s0) {
  int b = blockIdx.x >> 10;
  int chunk = blockIdx.x & 1023;
  int c = threadIdx.x;
  size_t base = ((size_t)b * 65536 + chunk * 64) * 192;
  float acc = 0.f;
  for (int p = 0; p < 64; ++p) acc += __bfloat162float(y[base + (size_t)p * 192 + c]);
  atomicAdd(&s0[b * 192 + c], acc);
}

// ---------------- SE gate: sigmoid(relu(mean@W1^T)@W2^T) ----------------
__global__ __launch_bounds__(256) void k_se(const float* __restrict__ s0, const float* __restrict__ w1,
                                            const float* __restrict__ w2, float* __restrict__ sg) {
  __shared__ float mean[192];
  __shared__ float t[24];
  int b = blockIdx.x;
  int tid = threadIdx.x;
  if (tid < 192) mean[tid] = s0[b * 192 + tid] * (1.f / 65536.f);
  __syncthreads();
  if (tid < 24) {
    float a = 0.f;
    for (int c = 0; c < 192; ++c) a += mean[c] * w1[tid * 192 + c];
    t[tid] = fmaxf(a, 0.f);
  }
  __syncthreads();
  if (tid < 192) {
    float a = 0.f;
    for (int r = 0; r < 24; ++r) a += t[r] * w2[tid * 24 + r];
    sg[b * 192 + tid] = 1.f / (1.f + expf(-a));
  }
}

// ---------------- fused: shift-gather + LN1 + QKV + attention + proj + reverse-shift + residual ----------------
// one block per window (2048 blocks, 256 threads), writes x1 into d_out
__global__ __launch_bounds__(256) void k_attn_fused(const float* __restrict__ x, const float* __restrict__ g,
                                                    const float* __restrict__ bb, const float* __restrict__ qkvw,
                                                    const float* __restrict__ qkvb, const float* __restrict__ rpb,
                                                    const float* __restrict__ projw, const float* __restrict__ projb,
                                                    float* __restrict__ x1out) {
  __shared__ __align__(16) char smem[55296];
  bf16 (*xw)[200] = (bf16(*)[200])(smem);           // 25,600 B  (dead after last head's QKV)
  bf16 (*qh)[34]  = (bf16(*)[34])(smem + 25600);    //  4,352 B per-head q
  bf16 (*kh)[34]  = (bf16(*)[34])(smem + 29952);    //  4,352 B per-head k
  bf16 (*vh)[34]  = (bf16(*)[34])(smem + 34304);    //  4,352 B per-head v
  float (*sc)[65] = (float(*)[65])(smem + 38656);   // 16,640 B scores -> total 55,296
  bf16 (*ob)[200] = (bf16(*)[200])(smem);           // aliases xw after head loop

  int win = blockIdx.x;
  int b = win >> 10;
  int wrem = win & 1023;
  int wh = wrem >> 5, ww = wrem & 31;
  int tid = threadIdx.x;
  int wave = tid >> 6, lane = tid & 63;

  // Phase A: gather (roll -4) + LN1 -> xw (bf16)
  for (int t = wave; t < 64; t += 4) {
    int i = t >> 3, j = t & 7;
    int hp = (wh * 8 + i + 4) & 255;
    int wp = (ww * 8 + j + 4) & 255;
    const float* xr = x + (((size_t)b << 16) + (hp << 8) + wp) * 192;
    float v0 = xr[lane], v1 = xr[lane + 64], v2 = xr[lane + 128];
    float s = v0 + v1 + v2;
    for (int o = 32; o > 0; o >>= 1) s += __shfl_down(s, o);
    s = __shfl(s, 0);
    float m = s * (1.f / 192.f);
    float d0 = v0 - m, d1 = v1 - m, d2 = v2 - m;
    float q = d0 * d0 + d1 * d1 + d2 * d2;
    for (int o = 32; o > 0; o >>= 1) q += __shfl_down(q, o);
    q = __shfl(q, 0);
    float inv = rsqrtf(q * (1.f / 192.f) + 1e-5f);
    xw[t][lane]       = __float2bfloat16(d0 * inv * g[lane]       + bb[lane]);
    xw[t][lane + 64]  = __float2bfloat16(d1 * inv * g[lane + 64]  + bb[lane + 64]);
    xw[t][lane + 128] = __float2bfloat16(d2 * inv * g[lane + 128] + bb[lane + 128]);
  }
  __syncthreads();

  // per-thread output slice: token n0, channels [slot*48, slot*48+48)
  int n0 = tid >> 2, slot = tid & 3;
  float oacc[48];

  const float scale = 0.17677669529663687f;  // 1/sqrt(32)
  for (int h = 0; h < 6; ++h) {
    // Phase B: q/k/v for head h (6144 dots of length 192)
    for (int idx = tid; idx < 6144; idx += 256) {
      int which = idx >> 11;
      int rem = idx & 2047;
      int n = rem >> 5, d = rem & 31;
      int col = which * 192 + h * 32 + d;
      const float* wr = qkvw + (size_t)col * 192;
      float acc = qkvb[col];
      for (int c = 0; c < 192; ++c) acc += __bfloat162float(xw[n][c]) * wr[c];
      bf16 val = __float2bfloat16(acc);
      if (which == 0) qh[n][d] = val;
      else if (which == 1) kh[n][d] = val;
      else vh[n][d] = val;
    }
    __syncthreads();

    // Phase C: scores = scale*q.k + rel-pos bias + shift mask
    for (int idx = tid; idx < 4096; idx += 256) {
      int n = idx >> 6, m = idx & 63;
      float acc = 0.f;
      for (int d = 0; d < 32; ++d) acc += __bfloat162float(qh[n][d]) * __bfloat162float(kh[m][d]);
      acc *= scale;
      int i1 = n >> 3, j1 = n & 7, i2 = m >> 3, j2 = m & 7;
      acc += rpb[((i1 - i2 + 7) * 15 + (j1 - j2 + 7)) * 6 + h];
      int l1 = region256(wh * 8 + i1) * 3 + region256(ww * 8 + j1);
      int l2 = region256(wh * 8 + i2) * 3 + region256(ww * 8 + j2);
      if (l1 != l2) acc -= 100.f;
      sc[n][m] = acc;
    }
    __syncthreads();

    // softmax: wave w handles rows w*16..w*16+15, lane-parallel over the 64 cols
    for (int r = 0; r < 16; ++r) {
      int n = wave * 16 + r;
      float v = sc[n][lane];
      float mx = v;
      for (int o = 32; o > 0; o >>= 1) mx = fmaxf(mx, __shfl_xor(mx, o));
      float e = __expf(v - mx);
      float ssum = e;
      for (int o = 32; o > 0; o >>= 1) ssum += __shfl_xor(ssum, o);
      sc[n][lane] = e / ssum;
    }
    __syncthreads();

    // PV into registers: this head's channels [32h, 32h+32) ∩ this thread's slice
    int lo = max(32 * h, slot * 48);
    int hi = min(32 * h + 32, slot * 48 + 48);
    for (int c = lo; c < hi; ++c) {
      int d = c - 32 * h;
      float acc = 0.f;
      for (int m = 0; m < 64; ++m) acc += sc[n0][m] * __bfloat162float(vh[m][d]);
      oacc[c - slot * 48] = acc;
    }
    __syncthreads();  // before next head overwrites qh/kh/vh/sc
  }

  // Phase D: registers -> LDS ob (reuses xw region), then proj + scatter + residual
  for (int c = 0; c < 48; ++c) ob[n0][slot * 48 + c] = __float2bfloat16(oacc[c]);
  __syncthreads();
  for (int idx = tid; idx < 64 * 192; idx += 256) {
    int n = idx / 192, c = idx - n * 192;
    const float* wr = projw + (size_t)c * 192;
    float acc = projb[c];
    for (int cc = 0; cc < 192; ++cc) acc += __bfloat162float(ob[n][cc]) * wr[cc];
    int i = n >> 3, j = n & 7;
    int hd2 = (wh * 8 + i + 4) & 255;  // reverse shift (scatter form of roll +4)
    int wd2 = (ww * 8 + j + 4) & 255;
    size_t p = (((size_t)b << 16) + (hd2 << 8) + wd2) * 192 + c;
    x1out[p] = x[p] + acc;
  }
}

// ---------------- fused MLP: LN2 + fc1 + exact GELU + fc2 + residual (in-place on d_out) ----------------
__global__ __launch_bounds__(256) void k_mlp_fused(float* __restrict__ x1, const float* __restrict__ g,
                                                   const float* __restrict__ bb, const float* __restrict__ w1,
                                                   const float* __restrict__ b1, const float* __restrict__ w2,
                                                   const float* __restrict__ b2) {
  __shared__ bf16 xl[32][200];  // 12,800 B
  __shared__ bf16 hh[32][772];  // 49,408 B  -> 62,208 total
  int wave = threadIdx.x >> 6, lane = threadIdx.x & 63;
  size_t tokbase = (size_t)blockIdx.x * 32;
  for (int t = wave; t < 32; t += 4) {
    const float* xr = x1 + (tokbase + t) * 192;
    float v0 = xr[lane], v1 = xr[lane + 64], v2 = xr[lane + 128];
    float s = v0 + v1 + v2;
    for (int o = 32; o > 0; o >>= 1) s += __shfl_down(s, o);
    s = __shfl(s, 0);
    float m = s * (1.f / 192.f);
    float d0 = v0 - m, d1 = v1 - m, d2 = v2 - m;
    float qq = d0 * d0 + d1 * d1 + d2 * d2;
    for (int o = 32; o > 0; o >>= 1) qq += __shfl_down(qq, o);
    qq = __shfl(qq, 0);
    float inv = rsqrtf(qq * (1.f / 192.f) + 1e-5f);
    xl[t][lane]       = __float2bfloat16(d0 * inv * g[lane]       + bb[lane]);
    xl[t][lane + 64]  = __float2bfloat16(d1 * inv * g[lane + 64]  + bb[lane + 64]);
    xl[t][lane + 128] = __float2bfloat16(d2 * inv * g[lane + 128] + bb[lane + 128]);
  }
  __syncthreads();
  // fc1 + exact GELU -> hh
  for (int idx = threadIdx.x; idx < 32 * 768; idx += 256) {
    int o = idx >> 5, n = idx & 31;
    const float* wr = w1 + (size_t)o * 192;
    float acc = b1[o];
    for (int c = 0; c < 192; ++c) acc += __bfloat162float(xl[n][c]) * wr[c];
    float ge = acc * 0.5f * (1.f + erff(acc * 0.70710678118654752f));
    hh[n][o] = __float2bfloat16(ge);
  }
  __syncthreads();
  // fc2 + residual, in-place (each element read then written by the same thread)
  for (int idx = threadIdx.x; idx < 32 * 192; idx += 256) {
    int c = idx >> 5, n = idx & 31;
    const float* wr = w2 + (size_t)c * 768;
    float acc = b2[c];
    for (int kk = 0; kk < 768; ++kk) acc += __bfloat162float(hh[n][kk]) * wr[kk];
    size_t p = (tokbase + n) * 192 + c;
    x1[p] = x1[p] + acc;
  }
}

// ---------------- out += y * gate ----------------
__global__ __launch_bounds__(256) void k_final(float* __restrict__ out, const bf16* __restrict__ y,
                                               const float* __restrict__ sg) {
  size_t i = (size_t)blockIdx.x * 256 + threadIdx.x;  // total 25165824
  int c = (int)(i % 192);
  size_t pix = i / 192;
  int b = (int)(pix >> 16);
  out[i] += __bfloat162float(y[i]) * sg[b * 192 + c];
}

extern "C" void kernel_launch(void* const* d_in, const int* in_sizes, int n_in,
                              void* d_out, int out_size, void* d_ws, size_t ws_size,
                              hipStream_t stream) {
  const float* x     = (const float*)d_in[0];
  const float* n1g   = (const float*)d_in[1];
  const float* n1b   = (const float*)d_in[2];
  const float* qkvw  = (const float*)d_in[3];
  const float* qkvb  = (const float*)d_in[4];
  const float* rpb   = (const float*)d_in[5];
  const float* projw = (const float*)d_in[6];
  const float* projb = (const float*)d_in[7];
  const float* n2g   = (const float*)d_in[8];
  const float* n2b   = (const float*)d_in[9];
  const float* w1    = (const float*)d_in[10];
  const float* b1    = (const float*)d_in[11];
  const float* w2    = (const float*)d_in[12];
  const float* b2    = (const float*)d_in[13];
  const float* c1w   = (const float*)d_in[14];
  const float* c1b   = (const float*)d_in[15];
  const float* c2w   = (const float*)d_in[16];
  const float* c2b   = (const float*)d_in[17];
  const float* c3w   = (const float*)d_in[18];
  const float* c3b   = (const float*)d_in[19];
  const float* sfc1  = (const float*)d_in[20];
  const float* sfc2  = (const float*)d_in[21];
  float* out = (float*)d_out;

  if (ws_size < WS_NEEDED) return;

  char* ws = (char*)d_ws;
  bf16*  ybf = (bf16*)(ws + OFF_Y);
  float* t1  = (float*)(ws + OFF_T1);
  float* t2  = (float*)(ws + OFF_T2);
  float* s0  = (float*)(ws + OFF_S0);
  float* sg  = (float*)(ws + OFF_SG);

  hipMemsetAsync(s0, 0, 384 * sizeof(float), stream);

  // LCE path (LN1 computed inline)
  k_ln_lce1<<<NTOK / 64, 256, 0, stream>>>(x, n1g, n1b, c1w, c1b, t1);
  k_lce2<<<(NTOK * 24) / 256, 256, 0, stream>>>(t1, c2w, c2b, t2);
  k_lce3<<<(NTOK * 192) / 256, 256, 0, stream>>>(t2, c3w, c3b, ybf);
  k_pool<<<2048, 192, 0, stream>>>(ybf, s0);
  k_se<<<2, 256, 0, stream>>>(s0, sfc1, sfc2, sg);
  // attention path (LN1 inline, writes x1 into d_out)
  k_attn_fused<<<2048, 256, 0, stream>>>(x, n1g, n1b, qkvw, qkvb, rpb, projw, projb, out);
  // MLP in-place on d_out
  k_mlp_fused<<<NTOK / 32, 256, 0, stream>>>(out, n2g, n2b, w1, b1, w2, b2);
  // final: out = x2 + y * gate
  k_final<<<(NTOK * 192) / 256, 256, 0, stream>>>(out, ybf, sg);
}

// Round 3
// 1632.343 us; speedup vs baseline: 9.3237x; 9.3237x over previous
//
#include <hip/hip_runtime.h>
#include <hip/hip_bf16.h>

using bf16 = __hip_bfloat16;
typedef __attribute__((ext_vector_type(8))) short short8;
typedef __attribute__((ext_vector_type(4))) float float4v;

constexpr int NTOK = 131072;  // 2*256*256

// ---------------- workspace layout (bytes) ----------------
constexpr size_t OFF_Y    = 0;           // bf16 [2][65536][192]  50,331,648
constexpr size_t OFF_T1   = 50331648;    // f32  [131072][24]     12,582,912
constexpr size_t OFF_T2   = 62914560;    // f32  [131072][24]     12,582,912
constexpr size_t OFF_S0   = 75497472;    // f32  [2][192]
constexpr size_t OFF_SG   = 75499008;    // f32  [2][192]
constexpr size_t OFF_WQKV = 75500544;    // bf16 [576][192]       221,184
constexpr size_t OFF_WPRJ = 75721728;    // bf16 [192][192]        73,728
constexpr size_t OFF_WFC1 = 75795456;    // bf16 [768][192]       294,912
constexpr size_t OFF_WFC2 = 76090368;    // bf16 [192][768]       294,912
constexpr size_t WS_NEEDED = 76385280;

__device__ __forceinline__ int region256(int t) { return t < 248 ? 0 : (t < 252 ? 1 : 2); }

__device__ __forceinline__ short8 lds8(const bf16* p) {
  return *reinterpret_cast<const short8*>(p);
}
__device__ __forceinline__ short8 glb8(const bf16* p) {
  return *reinterpret_cast<const short8*>(p);
}

// ---------------- fp32 -> bf16 weight convert ----------------
__global__ __launch_bounds__(256) void k_f2b(const float* __restrict__ s, bf16* __restrict__ d, int n) {
  int i = blockIdx.x * 256 + threadIdx.x;
  if (i < n) d[i] = __float2bfloat16(s[i]);
}

// ---------------- LN1 + LCE conv1x1 192->24 (fused) ----------------
__global__ __launch_bounds__(256) void k_ln_lce1(const float* __restrict__ x, const float* __restrict__ g,
                                                 const float* __restrict__ bb, const float* __restrict__ w,
                                                 const float* __restrict__ bia, float* __restrict__ t1) {
  __shared__ float xl[64][193];
  int wave = threadIdx.x >> 6, lane = threadIdx.x & 63;
  size_t tokbase = (size_t)blockIdx.x * 64;
  for (int t = wave; t < 64; t += 4) {
    const float* xr = x + (tokbase + t) * 192;
    float v0 = xr[lane], v1 = xr[lane + 64], v2 = xr[lane + 128];
    float s = v0 + v1 + v2;
    for (int o = 32; o > 0; o >>= 1) s += __shfl_down(s, o);
    s = __shfl(s, 0);
    float m = s * (1.f / 192.f);
    float d0 = v0 - m, d1 = v1 - m, d2 = v2 - m;
    float q = d0 * d0 + d1 * d1 + d2 * d2;
    for (int o = 32; o > 0; o >>= 1) q += __shfl_down(q, o);
    q = __shfl(q, 0);
    float inv = rsqrtf(q * (1.f / 192.f) + 1e-5f);
    xl[t][lane]       = d0 * inv * g[lane]       + bb[lane];
    xl[t][lane + 64]  = d1 * inv * g[lane + 64]  + bb[lane + 64];
    xl[t][lane + 128] = d2 * inv * g[lane + 128] + bb[lane + 128];
  }
  __syncthreads();
  for (int idx = threadIdx.x; idx < 64 * 24; idx += 256) {
    int n = idx / 24, rr = idx - n * 24;
    const float* wr = w + rr * 192;
    float acc = bia[rr];
    for (int c = 0; c < 192; ++c) acc += xl[n][c] * wr[c];
    t1[(tokbase + n) * 24 + rr] = acc;
  }
}

// ---------------- LCE conv3x3 24->24, LDS-tiled (16x16 tile + halo) ----------------
__global__ __launch_bounds__(256) void k_lce2t(const float* __restrict__ t1, const float* __restrict__ w,
                                               const float* __restrict__ bia, float* __restrict__ t2) {
  __shared__ float halo[18 * 18 * 25];   // channel pad 24->25 kills bank conflicts
  __shared__ float wlds[5184];           // [ro][ri][ky][kx]
  int bid = blockIdx.x;                  // 512 = 2 * 16 * 16
  int b = bid >> 8;
  int rem = bid & 255;
  int ty0 = ((rem >> 4) & 15) * 16, tx0 = (rem & 15) * 16;
  for (int idx = threadIdx.x; idx < 5184; idx += 256) wlds[idx] = w[idx];
  for (int idx = threadIdx.x; idx < 18 * 18 * 24; idx += 256) {
    int ch = idx % 24;
    int pp = idx / 24;
    int hy = pp / 18, hx = pp - hy * 18;
    int gy = ty0 + hy - 1, gx = tx0 + hx - 1;
    float v = 0.f;
    if (gy >= 0 && gy < 256 && gx >= 0 && gx < 256)
      v = t1[((size_t)(b << 16) + (gy << 8) + gx) * 24 + ch];
    halo[pp * 25 + ch] = v;
  }
  __syncthreads();
  int py = threadIdx.x >> 4, px = threadIdx.x & 15;
  float acc[24];
#pragma unroll
  for (int ro = 0; ro < 24; ++ro) acc[ro] = bia[ro];
  for (int ky = 0; ky < 3; ++ky) {
    for (int kx = 0; kx < 3; ++kx) {
      int base = ((py + ky) * 18 + px + kx) * 25;
      float inb[24];
#pragma unroll
      for (int ri = 0; ri < 24; ++ri) inb[ri] = halo[base + ri];
      int wo = ky * 3 + kx;
#pragma unroll
      for (int ro = 0; ro < 24; ++ro) {
        float a = acc[ro];
#pragma unroll
        for (int ri = 0; ri < 24; ++ri) a += inb[ri] * wlds[ro * 216 + ri * 9 + wo];
        acc[ro] = a;
      }
    }
  }
  size_t pix = (size_t)(b << 16) + ((ty0 + py) << 8) + tx0 + px;
#pragma unroll
  for (int ro = 0; ro < 24; ++ro) t2[pix * 24 + ro] = acc[ro];
}

// ---------------- LCE conv1x1 24->192 + LeakyReLU(0.2) -> y (bf16) ----------------
__global__ __launch_bounds__(256) void k_lce3(const float* __restrict__ t2, const float* __restrict__ w,
                                              const float* __restrict__ bia, bf16* __restrict__ y) {
  size_t tid = (size_t)blockIdx.x * 256 + threadIdx.x;
  int c = (int)(tid % 192);
  size_t pix = tid / 192;
  const float* ir = t2 + pix * 24;
  const float* wr = w + c * 24;
  float acc = bia[c];
  for (int ri = 0; ri < 24; ++ri) acc += ir[ri] * wr[ri];
  if (acc < 0.f) acc *= 0.2f;
  y[tid] = __float2bfloat16(acc);
}

// ---------------- global avg pool partial sums ----------------
__global__ __launch_bounds__(192) void k_pool(const bf16* __restrict__ y, float* __restrict__ s0) {
  int b = blockIdx.x >> 10;
  int chunk = blockIdx.x & 1023;
  int c = threadIdx.x;
  size_t base = ((size_t)b * 65536 + chunk * 64) * 192;
  float acc = 0.f;
  for (int p = 0; p < 64; ++p) acc += __bfloat162float(y[base + (size_t)p * 192 + c]);
  atomicAdd(&s0[b * 192 + c], acc);
}

// ---------------- SE gate ----------------
__global__ __launch_bounds__(256) void k_se(const float* __restrict__ s0, const float* __restrict__ w1,
                                            const float* __restrict__ w2, float* __restrict__ sg) {
  __shared__ float mean[192];
  __shared__ float t[24];
  int b = blockIdx.x;
  int tid = threadIdx.x;
  if (tid < 192) mean[tid] = s0[b * 192 + tid] * (1.f / 65536.f);
  __syncthreads();
  if (tid < 24) {
    float a = 0.f;
    for (int c = 0; c < 192; ++c) a += mean[c] * w1[tid * 192 + c];
    t[tid] = fmaxf(a, 0.f);
  }
  __syncthreads();
  if (tid < 192) {
    float a = 0.f;
    for (int r = 0; r < 24; ++r) a += t[r] * w2[tid * 24 + r];
    sg[b * 192 + tid] = 1.f / (1.f + expf(-a));
  }
}

// ---------------- MFMA attention: gather+LN1+QKV+attn+proj+scatter+residual ----------------
// 2048 blocks (one per window), 256 threads, dynamic LDS 80,664 B
constexpr int SMEM_ATTN = 80664;
__global__ __launch_bounds__(256, 2) void k_attn_mfma(const float* __restrict__ x, const float* __restrict__ g,
                                                      const float* __restrict__ bb, const bf16* __restrict__ wq,
                                                      const float* __restrict__ qkvb, const float* __restrict__ rpb,
                                                      const bf16* __restrict__ wp, const float* __restrict__ projb,
                                                      float* __restrict__ x1out) {
  extern __shared__ char sm[];
  bf16 (*Xw)[200] = (bf16(*)[200])(sm);            // 25,600
  bf16 (*Ow)[200] = (bf16(*)[200])(sm + 25600);    // 25,600
  bf16 (*Qh)[40]  = (bf16(*)[40]) (sm + 51200);    //  5,120
  bf16 (*Kh)[40]  = (bf16(*)[40]) (sm + 56320);    //  5,120
  bf16 (*Vth)[72] = (bf16(*)[72])(sm + 61440);     //  4,608
  bf16 (*Pm)[72]  = (bf16(*)[72])(sm + 66048);     //  9,216
  float* rpbs     = (float*)(sm + 75264);          //  5,400

  int win = blockIdx.x;
  int b = win >> 10;
  int wrem = win & 1023;
  int wh = wrem >> 5, ww = wrem & 31;
  int tid = threadIdx.x;
  int wave = tid >> 6, lane = tid & 63;
  int colB = lane & 15, grp = lane >> 4;   // fragment coords
  const float scale = 0.17677669529663687f;

  for (int idx = tid; idx < 1350; idx += 256) rpbs[idx] = rpb[idx];

  // Phase A: gather (roll -4) + LN1 -> Xw bf16
  for (int t = wave; t < 64; t += 4) {
    int i = t >> 3, j = t & 7;
    int hp = (wh * 8 + i + 4) & 255;
    int wpp = (ww * 8 + j + 4) & 255;
    const float* xr = x + (((size_t)b << 16) + (hp << 8) + wpp) * 192;
    float v0 = xr[lane], v1 = xr[lane + 64], v2 = xr[lane + 128];
    float s = v0 + v1 + v2;
    for (int o = 32; o > 0; o >>= 1) s += __shfl_down(s, o);
    s = __shfl(s, 0);
    float m = s * (1.f / 192.f);
    float d0 = v0 - m, d1 = v1 - m, d2 = v2 - m;
    float q = d0 * d0 + d1 * d1 + d2 * d2;
    for (int o = 32; o > 0; o >>= 1) q += __shfl_down(q, o);
    q = __shfl(q, 0);
    float inv = rsqrtf(q * (1.f / 192.f) + 1e-5f);
    Xw[t][lane]       = __float2bfloat16(d0 * inv * g[lane]       + bb[lane]);
    Xw[t][lane + 64]  = __float2bfloat16(d1 * inv * g[lane + 64]  + bb[lane + 64]);
    Xw[t][lane + 128] = __float2bfloat16(d2 * inv * g[lane + 128] + bb[lane + 128]);
  }
  __syncthreads();

  int mt = wave;                 // this wave's M-tile (16 tokens)
  // Preload A-fragments of Xw for all 6 K-steps (persist across head loop)
  short8 axw[6];
#pragma unroll
  for (int kk = 0; kk < 6; ++kk) axw[kk] = lds8(&Xw[mt * 16 + colB][kk * 32 + 8 * grp]);

  // masks/bias row constants
  int l1r[4], i1r[4], j1r[4];
#pragma unroll
  for (int r = 0; r < 4; ++r) {
    int n = mt * 16 + 4 * grp + r;
    i1r[r] = n >> 3; j1r[r] = n & 7;
    l1r[r] = region256(wh * 8 + i1r[r]) * 3 + region256(ww * 8 + j1r[r]);
  }

  for (int h = 0; h < 6; ++h) {
    // ---- QKV GEMM for head h (this wave: M-tile mt, 6 col-tiles q0,q1,k0,k1,v0,v1)
    float4v aq[2] = {{0,0,0,0},{0,0,0,0}}, ak[2] = {{0,0,0,0},{0,0,0,0}}, av[2] = {{0,0,0,0},{0,0,0,0}};
#pragma unroll
    for (int kk = 0; kk < 6; ++kk) {
      int ko = kk * 32 + 8 * grp;
#pragma unroll
      for (int t = 0; t < 2; ++t) {
        int colq = h * 32 + 16 * t + colB;
        short8 bq = glb8(wq + (size_t)colq * 192 + ko);
        short8 bk = glb8(wq + (size_t)(192 + colq) * 192 + ko);
        short8 bv = glb8(wq + (size_t)(384 + colq) * 192 + ko);
        aq[t] = __builtin_amdgcn_mfma_f32_16x16x32_bf16(axw[kk], bq, aq[t], 0, 0, 0);
        ak[t] = __builtin_amdgcn_mfma_f32_16x16x32_bf16(axw[kk], bk, ak[t], 0, 0, 0);
        av[t] = __builtin_amdgcn_mfma_f32_16x16x32_bf16(axw[kk], bv, av[t], 0, 0, 0);
      }
    }
#pragma unroll
    for (int t = 0; t < 2; ++t) {
      int colq = h * 32 + 16 * t + colB;
      float bq = qkvb[colq], bk = qkvb[192 + colq], bv = qkvb[384 + colq];
#pragma unroll
      for (int r = 0; r < 4; ++r) {
        int row = mt * 16 + 4 * grp + r;
        Qh[row][16 * t + colB] = __float2bfloat16((aq[t][r] + bq) * scale);
        Kh[row][16 * t + colB] = __float2bfloat16(ak[t][r] + bk);
        Vth[16 * t + colB][row] = __float2bfloat16(av[t][r] + bv);
      }
    }
    __syncthreads();

    // ---- scores: S = Qs @ K^T (M-tile mt, 4 N-tiles), bias+mask+softmax in regs
    short8 aqf = lds8(&Qh[mt * 16 + colB][8 * grp]);
    float4v s[4];
#pragma unroll
    for (int nt = 0; nt < 4; ++nt) {
      short8 bk = lds8(&Kh[nt * 16 + colB][8 * grp]);
      float4v z = {0, 0, 0, 0};
      s[nt] = __builtin_amdgcn_mfma_f32_16x16x32_bf16(aqf, bk, z, 0, 0, 0);
    }
#pragma unroll
    for (int nt = 0; nt < 4; ++nt) {
      int m = nt * 16 + colB;
      int i2 = m >> 3, j2 = m & 7;
      int l2 = region256(wh * 8 + i2) * 3 + region256(ww * 8 + j2);
#pragma unroll
      for (int r = 0; r < 4; ++r) {
        float bias = rpbs[((i1r[r] - i2 + 7) * 15 + (j1r[r] - j2 + 7)) * 6 + h];
        s[nt][r] += bias + (l1r[r] != l2 ? -100.f : 0.f);
      }
    }
#pragma unroll
    for (int r = 0; r < 4; ++r) {
      float mx = fmaxf(fmaxf(s[0][r], s[1][r]), fmaxf(s[2][r], s[3][r]));
      mx = fmaxf(mx, __shfl_xor(mx, 1));
      mx = fmaxf(mx, __shfl_xor(mx, 2));
      mx = fmaxf(mx, __shfl_xor(mx, 4));
      mx = fmaxf(mx, __shfl_xor(mx, 8));
      float e0 = __expf(s[0][r] - mx), e1 = __expf(s[1][r] - mx);
      float e2 = __expf(s[2][r] - mx), e3 = __expf(s[3][r] - mx);
      float sum = e0 + e1 + e2 + e3;
      sum += __shfl_xor(sum, 1);
      sum += __shfl_xor(sum, 2);
      sum += __shfl_xor(sum, 4);
      sum += __shfl_xor(sum, 8);
      float inv = 1.f / sum;
      int row = mt * 16 + 4 * grp + r;
      Pm[row][0 * 16 + colB] = __float2bfloat16(e0 * inv);
      Pm[row][1 * 16 + colB] = __float2bfloat16(e1 * inv);
      Pm[row][2 * 16 + colB] = __float2bfloat16(e2 * inv);
      Pm[row][3 * 16 + colB] = __float2bfloat16(e3 * inv);
    }
    __syncthreads();

    // ---- PV: O_h = P @ V  (M-tile mt, 2 N-tiles of d, K=64 in 2 steps)
    float4v o0 = {0, 0, 0, 0}, o1 = {0, 0, 0, 0};
#pragma unroll
    for (int k0 = 0; k0 < 2; ++k0) {
      short8 ap = lds8(&Pm[mt * 16 + colB][k0 * 32 + 8 * grp]);
      short8 bv0 = lds8(&Vth[colB][k0 * 32 + 8 * grp]);
      short8 bv1 = lds8(&Vth[16 + colB][k0 * 32 + 8 * grp]);
      o0 = __builtin_amdgcn_mfma_f32_16x16x32_bf16(ap, bv0, o0, 0, 0, 0);
      o1 = __builtin_amdgcn_mfma_f32_16x16x32_bf16(ap, bv1, o1, 0, 0, 0);
    }
#pragma unroll
    for (int r = 0; r < 4; ++r) {
      int row = mt * 16 + 4 * grp + r;
      Ow[row][h * 32 + colB] = __float2bfloat16(o0[r]);
      Ow[row][h * 32 + 16 + colB] = __float2bfloat16(o1[r]);
    }
    __syncthreads();
  }

  // ---- proj: 64x192 @ 192x192 (M-tile mt, 12 N-tiles, 6 K-steps)
  float4v pac[12];
#pragma unroll
  for (int nt = 0; nt < 12; ++nt) pac[nt] = (float4v){0, 0, 0, 0};
  for (int kk = 0; kk < 6; ++kk) {
    short8 ao = lds8(&Ow[mt * 16 + colB][kk * 32 + 8 * grp]);
    int ko = kk * 32 + 8 * grp;
#pragma unroll
    for (int nt = 0; nt < 12; ++nt) {
      short8 bp = glb8(wp + (size_t)(nt * 16 + colB) * 192 + ko);
      pac[nt] = __builtin_amdgcn_mfma_f32_16x16x32_bf16(ao, bp, pac[nt], 0, 0, 0);
    }
  }
  // epilogue: +bias, +residual, reverse-shift scatter
#pragma unroll
  for (int r = 0; r < 4; ++r) {
    int n = mt * 16 + 4 * grp + r;
    int i = n >> 3, j = n & 7;
    int hd2 = (wh * 8 + i + 4) & 255;
    int wd2 = (ww * 8 + j + 4) & 255;
    size_t prow = (((size_t)b << 16) + (hd2 << 8) + wd2) * 192;
#pragma unroll
    for (int nt = 0; nt < 12; ++nt) {
      int c = nt * 16 + colB;
      x1out[prow + c] = x[prow + c] + pac[nt][r] + projb[c];
    }
  }
}

// ---------------- MFMA MLP: LN2 + fc1 + GELU + fc2 + residual (in-place) ----------------
__global__ __launch_bounds__(256, 2) void k_mlp_mfma(float* __restrict__ x1, const float* __restrict__ g,
                                                     const float* __restrict__ bb, const bf16* __restrict__ w1,
                                                     const float* __restrict__ b1, const bf16* __restrict__ w2,
                                                     const float* __restrict__ b2) {
  __shared__ bf16 xl[32][200];   // 12,800
  __shared__ bf16 hh[32][776];   // 49,664
  int tid = threadIdx.x;
  int wave = tid >> 6, lane = tid & 63;
  int colB = lane & 15, grp = lane >> 4;
  size_t tokbase = (size_t)blockIdx.x * 32;

  for (int t = wave; t < 32; t += 4) {
    const float* xr = x1 + (tokbase + t) * 192;
    float v0 = xr[lane], v1 = xr[lane + 64], v2 = xr[lane + 128];
    float s = v0 + v1 + v2;
    for (int o = 32; o > 0; o >>= 1) s += __shfl_down(s, o);
    s = __shfl(s, 0);
    float m = s * (1.f / 192.f);
    float d0 = v0 - m, d1 = v1 - m, d2 = v2 - m;
    float qq = d0 * d0 + d1 * d1 + d2 * d2;
    for (int o = 32; o > 0; o >>= 1) qq += __shfl_down(qq, o);
    qq = __shfl(qq, 0);
    float inv = rsqrtf(qq * (1.f / 192.f) + 1e-5f);
    xl[t][lane]       = __float2bfloat16(d0 * inv * g[lane]       + bb[lane]);
    xl[t][lane + 64]  = __float2bfloat16(d1 * inv * g[lane + 64]  + bb[lane + 64]);
    xl[t][lane + 128] = __float2bfloat16(d2 * inv * g[lane + 128] + bb[lane + 128]);
  }
  __syncthreads();

  // fc1: M=32 (2 tiles), N=768 (this wave: 12 tiles), K=192 (6 steps)
  short8 a1f[6][2];
#pragma unroll
  for (int kk = 0; kk < 6; ++kk) {
    a1f[kk][0] = lds8(&xl[colB][kk * 32 + 8 * grp]);
    a1f[kk][1] = lds8(&xl[16 + colB][kk * 32 + 8 * grp]);
  }
  for (int nn = 0; nn < 12; ++nn) {
    int nt = wave * 12 + nn;
    float4v c0 = {0, 0, 0, 0}, c1 = {0, 0, 0, 0};
#pragma unroll
    for (int kk = 0; kk < 6; ++kk) {
      short8 bw = glb8(w1 + (size_t)(nt * 16 + colB) * 192 + kk * 32 + 8 * grp);
      c0 = __builtin_amdgcn_mfma_f32_16x16x32_bf16(a1f[kk][0], bw, c0, 0, 0, 0);
      c1 = __builtin_amdgcn_mfma_f32_16x16x32_bf16(a1f[kk][1], bw, c1, 0, 0, 0);
    }
    int col = nt * 16 + colB;
    float bias = b1[col];
#pragma unroll
    for (int r = 0; r < 4; ++r) {
      float v0 = c0[r] + bias;
      float v1 = c1[r] + bias;
      v0 = v0 * 0.5f * (1.f + erff(v0 * 0.70710678118654752f));
      v1 = v1 * 0.5f * (1.f + erff(v1 * 0.70710678118654752f));
      hh[4 * grp + r][col] = __float2bfloat16(v0);
      hh[16 + 4 * grp + r][col] = __float2bfloat16(v1);
    }
  }
  __syncthreads();

  // fc2: M=32 (2 tiles), N=192 (this wave: 3 tiles), K=768 (24 steps)
  float4v d0[3] = {{0,0,0,0},{0,0,0,0},{0,0,0,0}};
  float4v d1[3] = {{0,0,0,0},{0,0,0,0},{0,0,0,0}};
  int ntb = wave * 3;
  for (int kk = 0; kk < 24; ++kk) {
    int ko = kk * 32 + 8 * grp;
    short8 h0 = lds8(&hh[colB][ko]);
    short8 h1 = lds8(&hh[16 + colB][ko]);
#pragma unroll
    for (int j = 0; j < 3; ++j) {
      short8 bw = glb8(w2 + (size_t)((ntb + j) * 16 + colB) * 768 + ko);
      d0[j] = __builtin_amdgcn_mfma_f32_16x16x32_bf16(h0, bw, d0[j], 0, 0, 0);
      d1[j] = __builtin_amdgcn_mfma_f32_16x16x32_bf16(h1, bw, d1[j], 0, 0, 0);
    }
  }
#pragma unroll
  for (int j = 0; j < 3; ++j) {
    int col = (ntb + j) * 16 + colB;
    float bias = b2[col];
#pragma unroll
    for (int r = 0; r < 4; ++r) {
      size_t p0 = (tokbase + 4 * grp + r) * 192 + col;
      size_t p1 = (tokbase + 16 + 4 * grp + r) * 192 + col;
      x1[p0] += d0[j][r] + bias;
      x1[p1] += d1[j][r] + bias;
    }
  }
}

// ---------------- out += y * gate ----------------
__global__ __launch_bounds__(256) void k_final(float* __restrict__ out, const bf16* __restrict__ y,
                                               const float* __restrict__ sg) {
  size_t i = (size_t)blockIdx.x * 256 + threadIdx.x;
  int c = (int)(i % 192);
  size_t pix = i / 192;
  int b = (int)(pix >> 16);
  out[i] += __bfloat162float(y[i]) * sg[b * 192 + c];
}

extern "C" void kernel_launch(void* const* d_in, const int* in_sizes, int n_in,
                              void* d_out, int out_size, void* d_ws, size_t ws_size,
                              hipStream_t stream) {
  const float* x     = (const float*)d_in[0];
  const float* n1g   = (const float*)d_in[1];
  const float* n1b   = (const float*)d_in[2];
  const float* qkvw  = (const float*)d_in[3];
  const float* qkvb  = (const float*)d_in[4];
  const float* rpb   = (const float*)d_in[5];
  const float* projw = (const float*)d_in[6];
  const float* projb = (const float*)d_in[7];
  const float* n2g   = (const float*)d_in[8];
  const float* n2b   = (const float*)d_in[9];
  const float* w1    = (const float*)d_in[10];
  const float* b1    = (const float*)d_in[11];
  const float* w2    = (const float*)d_in[12];
  const float* b2    = (const float*)d_in[13];
  const float* c1w   = (const float*)d_in[14];
  const float* c1b   = (const float*)d_in[15];
  const float* c2w   = (const float*)d_in[16];
  const float* c2b   = (const float*)d_in[17];
  const float* c3w   = (const float*)d_in[18];
  const float* c3b   = (const float*)d_in[19];
  const float* sfc1  = (const float*)d_in[20];
  const float* sfc2  = (const float*)d_in[21];
  float* out = (float*)d_out;

  if (ws_size < WS_NEEDED) return;

  char* ws = (char*)d_ws;
  bf16*  ybf  = (bf16*)(ws + OFF_Y);
  float* t1   = (float*)(ws + OFF_T1);
  float* t2   = (float*)(ws + OFF_T2);
  float* s0   = (float*)(ws + OFF_S0);
  float* sg   = (float*)(ws + OFF_SG);
  bf16*  wqkv = (bf16*)(ws + OFF_WQKV);
  bf16*  wprj = (bf16*)(ws + OFF_WPRJ);
  bf16*  wfc1 = (bf16*)(ws + OFF_WFC1);
  bf16*  wfc2 = (bf16*)(ws + OFF_WFC2);

  hipFuncSetAttribute((const void*)k_attn_mfma, hipFuncAttributeMaxDynamicSharedMemorySize, SMEM_ATTN);

  hipMemsetAsync(s0, 0, 384 * sizeof(float), stream);

  // weight conversions (bf16)
  k_f2b<<<(110592 + 255) / 256, 256, 0, stream>>>(qkvw, wqkv, 110592);
  k_f2b<<<(36864 + 255) / 256, 256, 0, stream>>>(projw, wprj, 36864);
  k_f2b<<<(147456 + 255) / 256, 256, 0, stream>>>(w1, wfc1, 147456);
  k_f2b<<<(147456 + 255) / 256, 256, 0, stream>>>(w2, wfc2, 147456);

  // LCE path
  k_ln_lce1<<<NTOK / 64, 256, 0, stream>>>(x, n1g, n1b, c1w, c1b, t1);
  k_lce2t<<<512, 256, 0, stream>>>(t1, c2w, c2b, t2);
  k_lce3<<<(NTOK * 192) / 256, 256, 0, stream>>>(t2, c3w, c3b, ybf);
  k_pool<<<2048, 192, 0, stream>>>(ybf, s0);
  k_se<<<2, 256, 0, stream>>>(s0, sfc1, sfc2, sg);
  // attention (writes x1 into d_out)
  k_attn_mfma<<<2048, 256, SMEM_ATTN, stream>>>(x, n1g, n1b, wqkv, qkvb, rpb, wprj, projb, out);
  // MLP in-place on d_out
  k_mlp_mfma<<<NTOK / 32, 256, 0, stream>>>(out, n2g, n2b, wfc1, b1, wfc2, b2);
  // final: out = x2 + y * gate
  k_final<<<(NTOK * 192) / 256, 256, 0, stream>>>(out, ybf, sg);
}

// Round 4
// 1563.298 us; speedup vs baseline: 9.7355x; 1.0442x over previous
//
#include <hip/hip_runtime.h>
#include <hip/hip_bf16.h>

using bf16 = __hip_bfloat16;
typedef __attribute__((ext_vector_type(8))) short short8;
typedef __attribute__((ext_vector_type(4))) float float4v;

constexpr int NTOK = 131072;  // 2*256*256

// ---------------- workspace layout (bytes) ----------------
constexpr size_t OFF_Y    = 0;           // bf16 [2][65536][192]  50,331,648
constexpr size_t OFF_T1   = 50331648;    // f32  [131072][24]     12,582,912
constexpr size_t OFF_T2   = 62914560;    // f32  [131072][24]     12,582,912
constexpr size_t OFF_S0   = 75497472;    // f32  [2][192]
constexpr size_t OFF_SG   = 75499008;    // f32  [2][192]
constexpr size_t OFF_WQKV = 75500544;    // bf16 [576][192]       221,184
constexpr size_t OFF_WPRJ = 75721728;    // bf16 [192][192]        73,728
constexpr size_t OFF_WFC1 = 75795456;    // bf16 [768][192]       294,912
constexpr size_t OFF_WFC2 = 76090368;    // bf16 [192][768]       294,912
constexpr size_t OFF_C1WB = 76385280;    // bf16 [32][192]         12,288 (rows 24..31 zero)
constexpr size_t WS_NEEDED = 76397568;

__device__ __forceinline__ int region256(int t) { return t < 248 ? 0 : (t < 252 ? 1 : 2); }

__device__ __forceinline__ short8 lds8(const bf16* p) {
  return *reinterpret_cast<const short8*>(p);
}
__device__ __forceinline__ short8 glb8(const bf16* p) {
  return *reinterpret_cast<const short8*>(p);
}

// ---------------- fp32 -> bf16 weight convert ----------------
__global__ __launch_bounds__(256) void k_f2b(const float* __restrict__ s, bf16* __restrict__ d, int n) {
  int i = blockIdx.x * 256 + threadIdx.x;
  if (i < n) d[i] = __float2bfloat16(s[i]);
}

// ---------------- LCE conv3x3 24->24, LDS-tiled ----------------
__global__ __launch_bounds__(256) void k_lce2t(const float* __restrict__ t1, const float* __restrict__ w,
                                               const float* __restrict__ bia, float* __restrict__ t2) {
  __shared__ float halo[18 * 18 * 25];
  __shared__ float wlds[5184];
  int bid = blockIdx.x;  // 512 = 2 * 16 * 16
  int b = bid >> 8;
  int rem = bid & 255;
  int ty0 = ((rem >> 4) & 15) * 16, tx0 = (rem & 15) * 16;
  for (int idx = threadIdx.x; idx < 5184; idx += 256) wlds[idx] = w[idx];
  for (int idx = threadIdx.x; idx < 18 * 18 * 24; idx += 256) {
    int ch = idx % 24;
    int pp = idx / 24;
    int hy = pp / 18, hx = pp - hy * 18;
    int gy = ty0 + hy - 1, gx = tx0 + hx - 1;
    float v = 0.f;
    if (gy >= 0 && gy < 256 && gx >= 0 && gx < 256)
      v = t1[((size_t)(b << 16) + (gy << 8) + gx) * 24 + ch];
    halo[pp * 25 + ch] = v;
  }
  __syncthreads();
  int py = threadIdx.x >> 4, px = threadIdx.x & 15;
  float acc[24];
#pragma unroll
  for (int ro = 0; ro < 24; ++ro) acc[ro] = bia[ro];
  for (int ky = 0; ky < 3; ++ky) {
    for (int kx = 0; kx < 3; ++kx) {
      int base = ((py + ky) * 18 + px + kx) * 25;
      float inb[24];
#pragma unroll
      for (int ri = 0; ri < 24; ++ri) inb[ri] = halo[base + ri];
      int wo = ky * 3 + kx;
#pragma unroll
      for (int ro = 0; ro < 24; ++ro) {
        float a = acc[ro];
#pragma unroll
        for (int ri = 0; ri < 24; ++ri) a += inb[ri] * wlds[ro * 216 + ri * 9 + wo];
        acc[ro] = a;
      }
    }
  }
  size_t pix = (size_t)(b << 16) + ((ty0 + py) << 8) + tx0 + px;
#pragma unroll
  for (int ro = 0; ro < 24; ++ro) t2[pix * 24 + ro] = acc[ro];
}

// ---------------- LCE conv1x1 24->192 + LeakyReLU -> y (bf16) ----------------
__global__ __launch_bounds__(256) void k_lce3(const float* __restrict__ t2, const float* __restrict__ w,
                                              const float* __restrict__ bia, bf16* __restrict__ y) {
  size_t tid = (size_t)blockIdx.x * 256 + threadIdx.x;
  int c = (int)(tid % 192);
  size_t pix = tid / 192;
  const float* ir = t2 + pix * 24;
  const float* wr = w + c * 24;
  float acc = bia[c];
  for (int ri = 0; ri < 24; ++ri) acc += ir[ri] * wr[ri];
  if (acc < 0.f) acc *= 0.2f;
  y[tid] = __float2bfloat16(acc);
}

// ---------------- global avg pool partial sums ----------------
__global__ __launch_bounds__(192) void k_pool(const bf16* __restrict__ y, float* __restrict__ s0) {
  int b = blockIdx.x >> 10;
  int chunk = blockIdx.x & 1023;
  int c = threadIdx.x;
  size_t base = ((size_t)b * 65536 + chunk * 64) * 192;
  float acc = 0.f;
  for (int p = 0; p < 64; ++p) acc += __bfloat162float(y[base + (size_t)p * 192 + c]);
  atomicAdd(&s0[b * 192 + c], acc);
}

// ---------------- SE gate ----------------
__global__ __launch_bounds__(256) void k_se(const float* __restrict__ s0, const float* __restrict__ w1,
                                            const float* __restrict__ w2, float* __restrict__ sg) {
  __shared__ float mean[192];
  __shared__ float t[24];
  int b = blockIdx.x;
  int tid = threadIdx.x;
  if (tid < 192) mean[tid] = s0[b * 192 + tid] * (1.f / 65536.f);
  __syncthreads();
  if (tid < 24) {
    float a = 0.f;
    for (int c = 0; c < 192; ++c) a += mean[c] * w1[tid * 192 + c];
    t[tid] = fmaxf(a, 0.f);
  }
  __syncthreads();
  if (tid < 192) {
    float a = 0.f;
    for (int r = 0; r < 24; ++r) a += t[r] * w2[tid * 24 + r];
    sg[b * 192 + tid] = 1.f / (1.f + expf(-a));
  }
}

// ---------------- one-barrier fused attention (+ LCE conv1) ----------------
// 2048 blocks (one per window), 256 threads, wave w owns rows 16w..16w+15.
// LN -> Xw(private rows); QKV+conv1 GEMM (B from global); Q->regs, K/Vt->shared LDS;
// ONE barrier; per-head scores/softmax/PV via per-wave scratch; proj; scatter.
constexpr int SMEM_ATTN2 = 88064;
__global__ __launch_bounds__(256, 1) void k_attn2(const float* __restrict__ x, const float* __restrict__ g,
                                                  const float* __restrict__ bb, const bf16* __restrict__ wq,
                                                  const float* __restrict__ qkvb, const float* __restrict__ rpb,
                                                  const bf16* __restrict__ wp, const float* __restrict__ projb,
                                                  const bf16* __restrict__ c1wb, const float* __restrict__ c1b,
                                                  float* __restrict__ t1, float* __restrict__ x1out) {
  extern __shared__ char sm[];
  bf16 (*Xw)[200] = (bf16(*)[200])(sm);            // 25,600  LN rows; later aliased as O rows (per-wave private)
  bf16 (*Kl)[200] = (bf16(*)[200])(sm + 25600);    // 25,600  K all heads [tok][h*32+d]
  bf16 (*Vt)[72]  = (bf16(*)[72]) (sm + 51200);    // 27,648  V^T [h*32+d][tok]
  bf16 (*Ps)[72]  = (bf16(*)[72]) (sm + 78848);    //  9,216  per-wave Q/P scratch rows [wave*16+i]

  int win = blockIdx.x;
  int b = win >> 10;
  int wrem = win & 1023;
  int wh = wrem >> 5, ww = wrem & 31;
  int tid = threadIdx.x;
  int wave = tid >> 6, lane = tid & 63;
  int colB = lane & 15, grp = lane >> 4;
  const float scale = 0.17677669529663687f;  // 1/sqrt(32)

  // ---- Phase 1: LN over this wave's 16 tokens (gather with roll -4)
  for (int t = 0; t < 16; ++t) {
    int tok = wave * 16 + t;
    int i = tok >> 3, j = tok & 7;
    int hp = (wh * 8 + i + 4) & 255;
    int wpp = (ww * 8 + j + 4) & 255;
    const float* xr = x + (((size_t)b << 16) + (hp << 8) + wpp) * 192;
    float v0 = xr[lane], v1 = xr[lane + 64], v2 = xr[lane + 128];
    float s = v0 + v1 + v2;
    for (int o = 32; o > 0; o >>= 1) s += __shfl_down(s, o);
    s = __shfl(s, 0);
    float m = s * (1.f / 192.f);
    float d0 = v0 - m, d1 = v1 - m, d2 = v2 - m;
    float q = d0 * d0 + d1 * d1 + d2 * d2;
    for (int o = 32; o > 0; o >>= 1) q += __shfl_down(q, o);
    q = __shfl(q, 0);
    float inv = rsqrtf(q * (1.f / 192.f) + 1e-5f);
    Xw[tok][lane]       = __float2bfloat16(d0 * inv * g[lane]       + bb[lane]);
    Xw[tok][lane + 64]  = __float2bfloat16(d1 * inv * g[lane + 64]  + bb[lane + 64]);
    Xw[tok][lane + 128] = __float2bfloat16(d2 * inv * g[lane + 128] + bb[lane + 128]);
  }

  // A-fragments of LN rows (same-wave LDS write->read, DS pipe in-order)
  short8 axw[6];
#pragma unroll
  for (int kk = 0; kk < 6; ++kk) axw[kk] = lds8(&Xw[wave * 16 + colB][kk * 32 + 8 * grp]);

  // ---- Phase 2: QKV GEMM + conv1, B-fragments straight from global bf16 weights
  float qreg[48];  // Q C-layout: qreg[nt*4+r], cols nt*16+colB
#pragma unroll
  for (int gq = 0; gq < 4; ++gq) {  // Q: nt 0..11
    float4v acc[3] = {{0,0,0,0},{0,0,0,0},{0,0,0,0}};
#pragma unroll
    for (int kk = 0; kk < 6; ++kk) {
#pragma unroll
      for (int j = 0; j < 3; ++j) {
        int col = (gq * 3 + j) * 16 + colB;
        acc[j] = __builtin_amdgcn_mfma_f32_16x16x32_bf16(axw[kk], glb8(wq + (size_t)col * 192 + kk * 32 + 8 * grp), acc[j], 0, 0, 0);
      }
    }
#pragma unroll
    for (int j = 0; j < 3; ++j) {
      int nt = gq * 3 + j;
      float bias = qkvb[nt * 16 + colB];
#pragma unroll
      for (int r = 0; r < 4; ++r) qreg[nt * 4 + r] = (acc[j][r] + bias) * scale;
    }
  }
  for (int gk = 4; gk < 8; ++gk) {  // K: nt 12..23
    float4v acc[3] = {{0,0,0,0},{0,0,0,0},{0,0,0,0}};
#pragma unroll
    for (int kk = 0; kk < 6; ++kk) {
#pragma unroll
      for (int j = 0; j < 3; ++j) {
        int col = (gk * 3 + j) * 16 + colB;
        acc[j] = __builtin_amdgcn_mfma_f32_16x16x32_bf16(axw[kk], glb8(wq + (size_t)col * 192 + kk * 32 + 8 * grp), acc[j], 0, 0, 0);
      }
    }
    for (int j = 0; j < 3; ++j) {
      int col = (gk * 3 + j) * 16 + colB;
      float bias = qkvb[col];
#pragma unroll
      for (int r = 0; r < 4; ++r)
        Kl[wave * 16 + 4 * grp + r][col - 192] = __float2bfloat16(acc[j][r] + bias);
    }
  }
  for (int gv = 8; gv < 12; ++gv) {  // V: nt 24..35 -> transposed into Vt
    float4v acc[3] = {{0,0,0,0},{0,0,0,0},{0,0,0,0}};
#pragma unroll
    for (int kk = 0; kk < 6; ++kk) {
#pragma unroll
      for (int j = 0; j < 3; ++j) {
        int col = (gv * 3 + j) * 16 + colB;
        acc[j] = __builtin_amdgcn_mfma_f32_16x16x32_bf16(axw[kk], glb8(wq + (size_t)col * 192 + kk * 32 + 8 * grp), acc[j], 0, 0, 0);
      }
    }
    for (int j = 0; j < 3; ++j) {
      int col = (gv * 3 + j) * 16 + colB;
      float bias = qkvb[col];
#pragma unroll
      for (int r = 0; r < 4; ++r)
        Vt[col - 384][wave * 16 + 4 * grp + r] = __float2bfloat16(acc[j][r] + bias);
    }
  }
  {  // conv1 (LCE): 2 N-tiles, weights zero-padded to 32 rows
    float4v acc[2] = {{0,0,0,0},{0,0,0,0}};
#pragma unroll
    for (int kk = 0; kk < 6; ++kk) {
#pragma unroll
      for (int j = 0; j < 2; ++j) {
        int row = j * 16 + colB;
        acc[j] = __builtin_amdgcn_mfma_f32_16x16x32_bf16(axw[kk], glb8(c1wb + (size_t)row * 192 + kk * 32 + 8 * grp), acc[j], 0, 0, 0);
      }
    }
#pragma unroll
    for (int j = 0; j < 2; ++j) {
      int ch = j * 16 + colB;
      if (ch < 24) {
        float bias = c1b[ch];
#pragma unroll
        for (int r = 0; r < 4; ++r) {
          int tok = wave * 16 + 4 * grp + r;
          int i = tok >> 3, jj = tok & 7;
          int hp = (wh * 8 + i + 4) & 255;
          int wpp = (ww * 8 + jj + 4) & 255;
          size_t pix = ((size_t)b << 16) + (hp << 8) + wpp;
          t1[pix * 24 + ch] = acc[j][r] + bias;
        }
      }
    }
  }
  __syncthreads();  // THE barrier: K/Vt now visible to all waves

  // row constants for bias/mask
  int l1r[4], i1r[4], j1r[4];
#pragma unroll
  for (int r = 0; r < 4; ++r) {
    int n = wave * 16 + 4 * grp + r;
    i1r[r] = n >> 3; j1r[r] = n & 7;
    l1r[r] = region256(wh * 8 + i1r[r]) * 3 + region256(ww * 8 + j1r[r]);
  }

  // ---- Phase 3: per-head attention (no barriers; Ps is per-wave private)
  for (int h = 0; h < 6; ++h) {
    // Q tile -> scratch -> A-frag
#pragma unroll
    for (int t = 0; t < 2; ++t)
#pragma unroll
      for (int r = 0; r < 4; ++r)
        Ps[wave * 16 + 4 * grp + r][t * 16 + colB] = __float2bfloat16(qreg[(h * 2 + t) * 4 + r]);
    short8 aq = lds8(&Ps[wave * 16 + colB][8 * grp]);

    float4v s[4];
#pragma unroll
    for (int nt = 0; nt < 4; ++nt) {
      short8 bk = lds8(&Kl[nt * 16 + colB][h * 32 + 8 * grp]);
      float4v z = {0, 0, 0, 0};
      s[nt] = __builtin_amdgcn_mfma_f32_16x16x32_bf16(aq, bk, z, 0, 0, 0);
    }
#pragma unroll
    for (int nt = 0; nt < 4; ++nt) {
      int m = nt * 16 + colB;
      int i2 = m >> 3, j2 = m & 7;
      int l2 = region256(wh * 8 + i2) * 3 + region256(ww * 8 + j2);
#pragma unroll
      for (int r = 0; r < 4; ++r) {
        float bias = rpb[((i1r[r] - i2 + 7) * 15 + (j1r[r] - j2 + 7)) * 6 + h];
        s[nt][r] += bias + (l1r[r] != l2 ? -100.f : 0.f);
      }
    }
#pragma unroll
    for (int r = 0; r < 4; ++r) {
      float mx = fmaxf(fmaxf(s[0][r], s[1][r]), fmaxf(s[2][r], s[3][r]));
      mx = fmaxf(mx, __shfl_xor(mx, 1));
      mx = fmaxf(mx, __shfl_xor(mx, 2));
      mx = fmaxf(mx, __shfl_xor(mx, 4));
      mx = fmaxf(mx, __shfl_xor(mx, 8));
      float e0 = __expf(s[0][r] - mx), e1 = __expf(s[1][r] - mx);
      float e2 = __expf(s[2][r] - mx), e3 = __expf(s[3][r] - mx);
      float sum = e0 + e1 + e2 + e3;
      sum += __shfl_xor(sum, 1);
      sum += __shfl_xor(sum, 2);
      sum += __shfl_xor(sum, 4);
      sum += __shfl_xor(sum, 8);
      float inv = 1.f / sum;
      int row = wave * 16 + 4 * grp + r;
      Ps[row][0 * 16 + colB] = __float2bfloat16(e0 * inv);
      Ps[row][1 * 16 + colB] = __float2bfloat16(e1 * inv);
      Ps[row][2 * 16 + colB] = __float2bfloat16(e2 * inv);
      Ps[row][3 * 16 + colB] = __float2bfloat16(e3 * inv);
    }
    short8 ap0 = lds8(&Ps[wave * 16 + colB][0 * 32 + 8 * grp]);
    short8 ap1 = lds8(&Ps[wave * 16 + colB][1 * 32 + 8 * grp]);

    float4v o0 = {0, 0, 0, 0}, o1 = {0, 0, 0, 0};
    o0 = __builtin_amdgcn_mfma_f32_16x16x32_bf16(ap0, lds8(&Vt[h * 32 + colB][8 * grp]), o0, 0, 0, 0);
    o0 = __builtin_amdgcn_mfma_f32_16x16x32_bf16(ap1, lds8(&Vt[h * 32 + colB][32 + 8 * grp]), o0, 0, 0, 0);
    o1 = __builtin_amdgcn_mfma_f32_16x16x32_bf16(ap0, lds8(&Vt[h * 32 + 16 + colB][8 * grp]), o1, 0, 0, 0);
    o1 = __builtin_amdgcn_mfma_f32_16x16x32_bf16(ap1, lds8(&Vt[h * 32 + 16 + colB][32 + 8 * grp]), o1, 0, 0, 0);
#pragma unroll
    for (int r = 0; r < 4; ++r) {
      int row = wave * 16 + 4 * grp + r;
      Xw[row][h * 32 + colB]      = __float2bfloat16(o0[r]);  // Xw now = O (per-wave rows)
      Xw[row][h * 32 + 16 + colB] = __float2bfloat16(o1[r]);
    }
  }

  // ---- Phase 4: proj + reverse-shift scatter + residual
  short8 ao[6];
#pragma unroll
  for (int kk = 0; kk < 6; ++kk) ao[kk] = lds8(&Xw[wave * 16 + colB][kk * 32 + 8 * grp]);
  for (int gp = 0; gp < 4; ++gp) {
    float4v acc[3] = {{0,0,0,0},{0,0,0,0},{0,0,0,0}};
#pragma unroll
    for (int kk = 0; kk < 6; ++kk) {
#pragma unroll
      for (int j = 0; j < 3; ++j) {
        int col = (gp * 3 + j) * 16 + colB;
        acc[j] = __builtin_amdgcn_mfma_f32_16x16x32_bf16(ao[kk], glb8(wp + (size_t)col * 192 + kk * 32 + 8 * grp), acc[j], 0, 0, 0);
      }
    }
#pragma unroll
    for (int j = 0; j < 3; ++j) {
      int col = (gp * 3 + j) * 16 + colB;
      float bias = projb[col];
#pragma unroll
      for (int r = 0; r < 4; ++r) {
        int n = wave * 16 + 4 * grp + r;
        int i = n >> 3, jj = n & 7;
        int hd2 = (wh * 8 + i + 4) & 255;
        int wd2 = (ww * 8 + jj + 4) & 255;
        size_t p = (((size_t)b << 16) + (hd2 << 8) + wd2) * 192 + col;
        x1out[p] = x[p] + acc[j][r] + bias;
      }
    }
  }
}

// ---------------- MFMA MLP: LN2 + fc1 + GELU + fc2 + residual (in-place) ----------------
__global__ __launch_bounds__(256, 2) void k_mlp_mfma(float* __restrict__ x1, const float* __restrict__ g,
                                                     const float* __restrict__ bb, const bf16* __restrict__ w1,
                                                     const float* __restrict__ b1, const bf16* __restrict__ w2,
                                                     const float* __restrict__ b2) {
  __shared__ bf16 xl[32][200];
  __shared__ bf16 hh[32][776];
  int tid = threadIdx.x;
  int wave = tid >> 6, lane = tid & 63;
  int colB = lane & 15, grp = lane >> 4;
  size_t tokbase = (size_t)blockIdx.x * 32;

  for (int t = wave; t < 32; t += 4) {
    const float* xr = x1 + (tokbase + t) * 192;
    float v0 = xr[lane], v1 = xr[lane + 64], v2 = xr[lane + 128];
    float s = v0 + v1 + v2;
    for (int o = 32; o > 0; o >>= 1) s += __shfl_down(s, o);
    s = __shfl(s, 0);
    float m = s * (1.f / 192.f);
    float d0 = v0 - m, d1 = v1 - m, d2 = v2 - m;
    float qq = d0 * d0 + d1 * d1 + d2 * d2;
    for (int o = 32; o > 0; o >>= 1) qq += __shfl_down(qq, o);
    qq = __shfl(qq, 0);
    float inv = rsqrtf(qq * (1.f / 192.f) + 1e-5f);
    xl[t][lane]       = __float2bfloat16(d0 * inv * g[lane]       + bb[lane]);
    xl[t][lane + 64]  = __float2bfloat16(d1 * inv * g[lane + 64]  + bb[lane + 64]);
    xl[t][lane + 128] = __float2bfloat16(d2 * inv * g[lane + 128] + bb[lane + 128]);
  }
  __syncthreads();

  short8 a1f[6][2];
#pragma unroll
  for (int kk = 0; kk < 6; ++kk) {
    a1f[kk][0] = lds8(&xl[colB][kk * 32 + 8 * grp]);
    a1f[kk][1] = lds8(&xl[16 + colB][kk * 32 + 8 * grp]);
  }
  for (int nn = 0; nn < 12; ++nn) {
    int nt = wave * 12 + nn;
    float4v c0 = {0, 0, 0, 0}, c1 = {0, 0, 0, 0};
#pragma unroll
    for (int kk = 0; kk < 6; ++kk) {
      short8 bw = glb8(w1 + (size_t)(nt * 16 + colB) * 192 + kk * 32 + 8 * grp);
      c0 = __builtin_amdgcn_mfma_f32_16x16x32_bf16(a1f[kk][0], bw, c0, 0, 0, 0);
      c1 = __builtin_amdgcn_mfma_f32_16x16x32_bf16(a1f[kk][1], bw, c1, 0, 0, 0);
    }
    int col = nt * 16 + colB;
    float bias = b1[col];
#pragma unroll
    for (int r = 0; r < 4; ++r) {
      float v0 = c0[r] + bias;
      float v1 = c1[r] + bias;
      v0 = v0 * 0.5f * (1.f + erff(v0 * 0.70710678118654752f));
      v1 = v1 * 0.5f * (1.f + erff(v1 * 0.70710678118654752f));
      hh[4 * grp + r][col] = __float2bfloat16(v0);
      hh[16 + 4 * grp + r][col] = __float2bfloat16(v1);
    }
  }
  __syncthreads();

  float4v d0[3] = {{0,0,0,0},{0,0,0,0},{0,0,0,0}};
  float4v d1[3] = {{0,0,0,0},{0,0,0,0},{0,0,0,0}};
  int ntb = wave * 3;
  for (int kk = 0; kk < 24; ++kk) {
    int ko = kk * 32 + 8 * grp;
    short8 h0 = lds8(&hh[colB][ko]);
    short8 h1 = lds8(&hh[16 + colB][ko]);
#pragma unroll
    for (int j = 0; j < 3; ++j) {
      short8 bw = glb8(w2 + (size_t)((ntb + j) * 16 + colB) * 768 + ko);
      d0[j] = __builtin_amdgcn_mfma_f32_16x16x32_bf16(h0, bw, d0[j], 0, 0, 0);
      d1[j] = __builtin_amdgcn_mfma_f32_16x16x32_bf16(h1, bw, d1[j], 0, 0, 0);
    }
  }
#pragma unroll
  for (int j = 0; j < 3; ++j) {
    int col = (ntb + j) * 16 + colB;
    float bias = b2[col];
#pragma unroll
    for (int r = 0; r < 4; ++r) {
      size_t p0 = (tokbase + 4 * grp + r) * 192 + col;
      size_t p1 = (tokbase + 16 + 4 * grp + r) * 192 + col;
      x1[p0] += d0[j][r] + bias;
      x1[p1] += d1[j][r] + bias;
    }
  }
}

// ---------------- out += y * gate ----------------
__global__ __launch_bounds__(256) void k_final(float* __restrict__ out, const bf16* __restrict__ y,
                                               const float* __restrict__ sg) {
  size_t i = (size_t)blockIdx.x * 256 + threadIdx.x;
  int c = (int)(i % 192);
  size_t pix = i / 192;
  int b = (int)(pix >> 16);
  out[i] += __bfloat162float(y[i]) * sg[b * 192 + c];
}

extern "C" void kernel_launch(void* const* d_in, const int* in_sizes, int n_in,
                              void* d_out, int out_size, void* d_ws, size_t ws_size,
                              hipStream_t stream) {
  const float* x     = (const float*)d_in[0];
  const float* n1g   = (const float*)d_in[1];
  const float* n1b   = (const float*)d_in[2];
  const float* qkvw  = (const float*)d_in[3];
  const float* qkvb  = (const float*)d_in[4];
  const float* rpb   = (const float*)d_in[5];
  const float* projw = (const float*)d_in[6];
  const float* projb = (const float*)d_in[7];
  const float* n2g   = (const float*)d_in[8];
  const float* n2b   = (const float*)d_in[9];
  const float* w1    = (const float*)d_in[10];
  const float* b1    = (const float*)d_in[11];
  const float* w2    = (const float*)d_in[12];
  const float* b2    = (const float*)d_in[13];
  const float* c1w   = (const float*)d_in[14];
  const float* c1b   = (const float*)d_in[15];
  const float* c2w   = (const float*)d_in[16];
  const float* c2b   = (const float*)d_in[17];
  const float* c3w   = (const float*)d_in[18];
  const float* c3b   = (const float*)d_in[19];
  const float* sfc1  = (const float*)d_in[20];
  const float* sfc2  = (const float*)d_in[21];
  float* out = (float*)d_out;

  if (ws_size < WS_NEEDED) return;

  char* ws = (char*)d_ws;
  bf16*  ybf  = (bf16*)(ws + OFF_Y);
  float* t1   = (float*)(ws + OFF_T1);
  float* t2   = (float*)(ws + OFF_T2);
  float* s0   = (float*)(ws + OFF_S0);
  float* sg   = (float*)(ws + OFF_SG);
  bf16*  wqkv = (bf16*)(ws + OFF_WQKV);
  bf16*  wprj = (bf16*)(ws + OFF_WPRJ);
  bf16*  wfc1 = (bf16*)(ws + OFF_WFC1);
  bf16*  wfc2 = (bf16*)(ws + OFF_WFC2);
  bf16*  c1wb = (bf16*)(ws + OFF_C1WB);

  hipFuncSetAttribute((const void*)k_attn2, hipFuncAttributeMaxDynamicSharedMemorySize, SMEM_ATTN2);

  hipMemsetAsync(s0, 0, 384 * sizeof(float), stream);
  hipMemsetAsync((char*)c1wb + 24 * 192 * sizeof(bf16), 0, 8 * 192 * sizeof(bf16), stream);

  k_f2b<<<(110592 + 255) / 256, 256, 0, stream>>>(qkvw, wqkv, 110592);
  k_f2b<<<(36864 + 255) / 256, 256, 0, stream>>>(projw, wprj, 36864);
  k_f2b<<<(147456 + 255) / 256, 256, 0, stream>>>(w1, wfc1, 147456);
  k_f2b<<<(147456 + 255) / 256, 256, 0, stream>>>(w2, wfc2, 147456);
  k_f2b<<<(4608 + 255) / 256, 256, 0, stream>>>(c1w, c1wb, 4608);

  // fused attention + LN1 + LCE conv1 (t1), writes x1 into d_out
  k_attn2<<<2048, 256, SMEM_ATTN2, stream>>>(x, n1g, n1b, wqkv, qkvb, rpb, wprj, projb,
                                             c1wb, c1b, t1, out);
  // LCE tail
  k_lce2t<<<512, 256, 0, stream>>>(t1, c2w, c2b, t2);
  k_lce3<<<(NTOK * 192) / 256, 256, 0, stream>>>(t2, c3w, c3b, ybf);
  k_pool<<<2048, 192, 0, stream>>>(ybf, s0);
  k_se<<<2, 256, 0, stream>>>(s0, sfc1, sfc2, sg);
  // MLP in-place on d_out
  k_mlp_mfma<<<NTOK / 32, 256, 0, stream>>>(out, n2g, n2b, wfc1, b1, wfc2, b2);
  // final: out = x2 + y * gate
  k_final<<<(NTOK * 192) / 256, 256, 0, stream>>>(out, ybf, sg);
}